// Round 3
// baseline (488.996 us; speedup 1.0000x reference)
//
#include <hip/hip_runtime.h>
#include <hip/hip_bf16.h>

// RGCN 2-layer forward, gather-formulation (zero accumulation atomics).
// Pipeline: sniff dtype -> hist(deg per dst) -> scan(CSR offsets) ->
// scatter(dst-sorted edge list, packed src|rel<<16) ->
// l1 (16 lanes/dst: mean-by-(rel,dst) via LDS hist, +root1+b1, relu) ->
// l2 (8 lanes/dst: dot(x[src],w2[rel]) mean-agg + x@root2+b2, log-softmax).
// src < 65536 is false (N=50000 < 65536) -> src packs in 16 bits, rel in 5.

constexpr int Nn = 50000;
constexpr int Hh = 16;
constexpr int Rr = 32;
constexpr int Cc = 8;
constexpr int Ee = 1600000;

__device__ __forceinline__ float b2f(__hip_bfloat16 v) { return __bfloat162float(v); }

// --- 0. dtype sniff (bf16 vs fp32 delivery) -----------------------------------
__global__ void sniff_kernel(const unsigned short* __restrict__ w, int* __restrict__ flag) {
    if (blockIdx.x == 0 && threadIdx.x == 0) {
        int hits = 0;
        for (int i = 0; i < 64; ++i) {
            unsigned short u = w[2 * i];
            int e = (u >> 7) & 0xFF;
            if (e >= 100 && e <= 130) ++hits;
        }
        *flag = (hits >= 32) ? 1 : 0;   // 1 = bf16, 0 = fp32
    }
}

// --- 1. degree histogram per dst ----------------------------------------------
__global__ void hist_kernel(const int* __restrict__ dst, int* __restrict__ deg) {
    int e = blockIdx.x * blockDim.x + threadIdx.x;
    if (e < Ee) atomicAdd(&deg[dst[e]], 1);
}

// --- 2. exclusive scan over deg -> offs[N+1] (single workgroup, wave scans) ---
__global__ __launch_bounds__(1024) void scan_kernel(const int* __restrict__ deg,
                                                    int* __restrict__ offs) {
    __shared__ int wsum[16];
    __shared__ int base;
    int tid = threadIdx.x, lane = tid & 63, w = tid >> 6;
    if (tid == 0) base = 0;
    __syncthreads();
    for (int start = 0; start < Nn; start += 1024) {
        int i = start + tid;
        int v = (i < Nn) ? deg[i] : 0;
        int s = v;
#pragma unroll
        for (int o = 1; o < 64; o <<= 1) { int t = __shfl_up(s, o, 64); if (lane >= o) s += t; }
        if (lane == 63) wsum[w] = s;
        __syncthreads();
        if (w == 0 && lane < 16) {
            int t = wsum[lane];
#pragma unroll
            for (int o = 1; o < 16; o <<= 1) { int u = __shfl_up(t, o, 64); if (lane >= o) t += u; }
            wsum[lane] = t;
        }
        __syncthreads();
        int wbase = (w > 0) ? wsum[w - 1] : 0;
        if (i < Nn) offs[i] = base + wbase + s - v;
        __syncthreads();
        if (tid == 0) base += wsum[15];
        __syncthreads();
    }
    if (threadIdx.x == 0) offs[Nn] = base;
}

// --- 3. scatter edges into dst-sorted order, packed src | rel<<16 -------------
__global__ void scatter_kernel(const int* __restrict__ src, const int* __restrict__ dst,
                               const int* __restrict__ et, const int* __restrict__ offs,
                               int* __restrict__ cursor, unsigned int* __restrict__ sorted) {
    int e = blockIdx.x * blockDim.x + threadIdx.x;
    if (e < Ee) {
        int d = dst[e];
        int pos = atomicAdd(&cursor[d], 1);
        sorted[offs[d] + pos] = (unsigned)src[e] | ((unsigned)et[e] << 16);
    }
}

// --- 4. layer 1: 16 lanes per dst, zero atomics, fused relu+root1+b1 ----------
__global__ __launch_bounds__(256) void l1_kernel(const unsigned int* __restrict__ sorted,
                                                 const int* __restrict__ offs,
                                                 const void* __restrict__ w1,
                                                 const void* __restrict__ root1,
                                                 const void* __restrict__ b1,
                                                 const int* __restrict__ flag,
                                                 float* __restrict__ x) {
    __shared__ int   hist[16 * 32];
    __shared__ float invh[16 * 32];
    int tid = threadIdx.x, g = tid >> 4, h = tid & 15;
    int d = blockIdx.x * 16 + g;              // grid 3125*16 == Nn exactly
    hist[tid] = 0; hist[tid + 256] = 0;
    __syncthreads();
    int off = offs[d], deg = offs[d + 1] - off;
    for (int i = h; i < deg; i += 16)
        atomicAdd(&hist[(g << 5) + (sorted[off + i] >> 16)], 1);
    __syncthreads();
    invh[tid]       = hist[tid]       > 0 ? 1.0f / (float)hist[tid]       : 0.0f;
    invh[tid + 256] = hist[tid + 256] > 0 ? 1.0f / (float)hist[tid + 256] : 0.0f;
    __syncthreads();
    float acc = 0.0f;
    int isbf = *flag;
    if (isbf) {
        const __hip_bfloat16* W = (const __hip_bfloat16*)w1;
        for (int i = 0; i < deg; ++i) {
            unsigned p = sorted[off + i];
            int rel = p >> 16, s = p & 0xFFFF;
            acc += b2f(W[((size_t)rel * Nn + s) * Hh + h]) * invh[(g << 5) + rel];
        }
        acc += b2f(((const __hip_bfloat16*)root1)[d * Hh + h])
             + b2f(((const __hip_bfloat16*)b1)[h]);
    } else {
        const float* W = (const float*)w1;
        for (int i = 0; i < deg; ++i) {
            unsigned p = sorted[off + i];
            int rel = p >> 16, s = p & 0xFFFF;
            acc += W[((size_t)rel * Nn + s) * Hh + h] * invh[(g << 5) + rel];
        }
        acc += ((const float*)root1)[d * Hh + h] + ((const float*)b1)[h];
    }
    x[d * Hh + h] = acc > 0.0f ? acc : 0.0f;
}

// --- 5. layer 2 + epilogue: 8 lanes per dst (one per class), zero atomics -----
__global__ __launch_bounds__(256) void l2_kernel(const unsigned int* __restrict__ sorted,
                                                 const int* __restrict__ offs,
                                                 const float* __restrict__ x,
                                                 const void* __restrict__ w2,
                                                 const void* __restrict__ root2,
                                                 const void* __restrict__ b2v,
                                                 const int* __restrict__ flag,
                                                 void* __restrict__ out) {
    __shared__ int   hist[32 * 32];
    __shared__ float invh[32 * 32];
    int tid = threadIdx.x, g = tid >> 3, c = tid & 7;
    int d = blockIdx.x * 32 + g;
    for (int k = tid; k < 1024; k += 256) hist[k] = 0;
    __syncthreads();
    int off = 0, deg = 0;
    if (d < Nn) { off = offs[d]; deg = offs[d + 1] - off; }
    for (int i = c; i < deg; i += 8)
        atomicAdd(&hist[(g << 5) + (sorted[off + i] >> 16)], 1);
    __syncthreads();
    for (int k = tid; k < 1024; k += 256)
        invh[k] = hist[k] > 0 ? 1.0f / (float)hist[k] : 0.0f;
    __syncthreads();
    if (d >= Nn) return;                      // no barriers after this point
    int isbf = *flag;
    float acc = 0.0f;
    for (int i = 0; i < deg; ++i) {
        unsigned p = sorted[off + i];
        int rel = p >> 16, s = p & 0xFFFF;
        const float4* xr = (const float4*)(x + (size_t)s * Hh);
        float xv[16];
        *(float4*)&xv[0]  = xr[0];
        *(float4*)&xv[4]  = xr[1];
        *(float4*)&xv[8]  = xr[2];
        *(float4*)&xv[12] = xr[3];
        float dot = 0.0f;
        if (isbf) {
            const __hip_bfloat16* W = (const __hip_bfloat16*)w2 + rel * (Hh * Cc) + c;
#pragma unroll
            for (int hh = 0; hh < Hh; ++hh) dot += xv[hh] * b2f(W[hh * Cc]);
        } else {
            const float* W = (const float*)w2 + rel * (Hh * Cc) + c;
#pragma unroll
            for (int hh = 0; hh < Hh; ++hh) dot += xv[hh] * W[hh * Cc];
        }
        acc += dot * invh[(g << 5) + rel];
    }
    // epilogue: + x[d] @ root2 + b2, then log-softmax over the 8 classes
    const float4* xd4 = (const float4*)(x + (size_t)d * Hh);
    float xd[16];
    *(float4*)&xd[0]  = xd4[0];
    *(float4*)&xd[4]  = xd4[1];
    *(float4*)&xd[8]  = xd4[2];
    *(float4*)&xd[12] = xd4[3];
    float v = acc;
    if (isbf) {
        v += b2f(((const __hip_bfloat16*)b2v)[c]);
#pragma unroll
        for (int hh = 0; hh < Hh; ++hh)
            v += xd[hh] * b2f(((const __hip_bfloat16*)root2)[hh * Cc + c]);
    } else {
        v += ((const float*)b2v)[c];
#pragma unroll
        for (int hh = 0; hh < Hh; ++hh)
            v += xd[hh] * ((const float*)root2)[hh * Cc + c];
    }
    float m = v;
#pragma unroll
    for (int o = 1; o < 8; o <<= 1) m = fmaxf(m, __shfl_xor(m, o, 8));
    float ex = expf(v - m);
    float ssum = ex;
#pragma unroll
    for (int o = 1; o < 8; o <<= 1) ssum += __shfl_xor(ssum, o, 8);
    float res = v - m - logf(ssum);
    if (isbf) ((__hip_bfloat16*)out)[d * Cc + c] = __float2bfloat16(res);
    else      ((float*)out)[d * Cc + c] = res;
}

extern "C" void kernel_launch(void* const* d_in, const int* in_sizes, int n_in,
                              void* d_out, int out_size, void* d_ws, size_t ws_size,
                              hipStream_t stream) {
    const int* edge_index = (const int*)d_in[0];     // [2, E]
    const int* src = edge_index;
    const int* dst = edge_index + Ee;
    const int* et  = (const int*)d_in[1];            // [E]
    const void* w1    = d_in[2];  // [R,N,H]
    const void* root1 = d_in[3];  // [N,H]
    const void* b1    = d_in[4];  // [H]
    const void* w2    = d_in[5];  // [R,H,C]
    const void* root2 = d_in[6];  // [H,C]
    const void* b2    = d_in[7];  // [C]

    // ws layout (ints): deg[50000] | cursor[50000] | offs[50004] |
    //                   sorted[1600000] | x(fp32)[800000] | flag[1]
    int* deg    = (int*)d_ws;
    int* cursor = deg + 50000;
    int* offs   = cursor + 50000;
    unsigned int* sorted = (unsigned int*)(offs + 50004);
    float* x    = (float*)(sorted + Ee);             // 16B-aligned (checked)
    int* flag   = (int*)(x + (size_t)Nn * Hh);

    hipMemsetAsync(d_ws, 0, 100000 * sizeof(int), stream);   // deg + cursor

    sniff_kernel<<<1, 64, 0, stream>>>((const unsigned short*)w1, flag);
    hist_kernel<<<(Ee + 255) / 256, 256, 0, stream>>>(dst, deg);
    scan_kernel<<<1, 1024, 0, stream>>>(deg, offs);
    scatter_kernel<<<(Ee + 255) / 256, 256, 0, stream>>>(src, dst, et, offs, cursor, sorted);
    l1_kernel<<<Nn / 16, 256, 0, stream>>>(sorted, offs, w1, root1, b1, flag, x);
    l2_kernel<<<(Nn + 31) / 32, 256, 0, stream>>>(sorted, offs, x, w2, root2, b2, flag, d_out);
}